// Round 5
// baseline (4986.335 us; speedup 1.0000x reference)
//
#include <hip/hip_runtime.h>

typedef _Float16 v8h __attribute__((ext_vector_type(8)));
typedef float v4f __attribute__((ext_vector_type(4)));

// ---- workspace layout (bytes) ----
#define OFF_BAR   0
#define OFF_AO0   4096
#define OFF_AO1   (OFF_AO0 + (1<<21))
#define OFF_AF0   (OFF_AO1 + (1<<21))
#define OFF_AF1   (OFF_AF0 + (1<<21))
#define OFF_W1    (OFF_AF1 + (1<<21))
#define OFF_W2    (OFF_W1 + (1<<21))
#define OFF_B1    (OFF_W2 + (1<<22))
#define OFF_B2    (OFF_B1 + 8192)

// Pack weights into MFMA B-fragment order:
// frag layout (16x16x32): n = nt*16 + (lane&15), k = k32*32 + (lane>>4)*8 + el
__global__ __launch_bounds__(256, 1)
void lstm_prep(const float* __restrict__ Whh1, const float* __restrict__ Wih2,
               const float* __restrict__ Whh2, const float* __restrict__ bih1,
               const float* __restrict__ bhh1, const float* __restrict__ bih2,
               const float* __restrict__ bhh2,
               _Float16* __restrict__ W1p, _Float16* __restrict__ W2p,
               float* __restrict__ bs1, float* __restrict__ bs2)
{
  const int total = 1048576 + 2097152 + 4096;
  for (int i = blockIdx.x*blockDim.x + threadIdx.x; i < total; i += gridDim.x*blockDim.x) {
    if (i < 1048576) {
      int nt = i >> 13, rem = i & 8191;
      int k32 = rem >> 9, c = rem & 511;
      int lane = c >> 3, el = c & 7;
      int n = nt*16 + (lane & 15);
      int k = k32*32 + (lane >> 4)*8 + el;
      W1p[i] = (_Float16)Whh1[n*512 + k];
    } else if (i < 3145728) {
      int j = i - 1048576;
      int nt = j >> 14, rem = j & 16383;
      int k32 = rem >> 9, c = rem & 511;
      int lane = c >> 3, el = c & 7;
      int n = nt*16 + (lane & 15);
      int k = k32*32 + (lane >> 4)*8 + el;
      float v = (k < 512) ? Wih2[n*512 + k] : Whh2[n*512 + (k - 512)];
      W2p[j] = (_Float16)v;
    } else {
      int n = i - 3145728;
      if (n < 2048) bs1[n] = bih1[n] + bhh1[n];
      else          bs2[n-2048] = bih2[n-2048] + bhh2[n-2048];
    }
  }
}

__device__ __forceinline__ float sigmoidf_(float z) { return 1.f / (1.f + __expf(-z)); }
__device__ __forceinline__ float tanhf_(float z)    { return 1.f - 2.f/(1.f + __expf(2.f*z)); }

// agent-scope relaxed 16B fragment load (2x8B): bypasses L1/L2, MALL-coherent
__device__ __forceinline__ v8h ld_frag_dev(const _Float16* p) {
  union { unsigned long long u[2]; v8h h; } cv;
  const unsigned long long* q = (const unsigned long long*)p;
  cv.u[0] = __hip_atomic_load(q,     __ATOMIC_RELAXED, __HIP_MEMORY_SCOPE_AGENT);
  cv.u[1] = __hip_atomic_load(q + 1, __ATOMIC_RELAXED, __HIP_MEMORY_SCOPE_AGENT);
  return cv.h;
}

// 256 blocks x 256 threads, persistent, FUSED pipeline: round r computes
// cell1-part (h1(t) or h1f(s)) and cell2-part (h2(t-1) or h2f(s-1)) concurrently
// -> 162 rounds instead of 320. Wave split: 2 m-tiles x half-K of both cells.
// Reduce: dump BOTH cells (64KB) -> sync -> combine into regs -> sync ->
// per-cell scatter -> sync -> epilogue  (R4's fused read+scatter clobbered the
// dump region mid-read — the syncs here are load-bearing).
__global__ __launch_bounds__(256, 1)
void lstm_main(const float* __restrict__ x, const float* __restrict__ Wih1,
               const float* __restrict__ Wl, const float* __restrict__ blv,
               _Float16* __restrict__ AO0, _Float16* __restrict__ AO1,
               _Float16* __restrict__ AF0, _Float16* __restrict__ AF1,
               const _Float16* __restrict__ W1, const _Float16* __restrict__ W2,
               const float* __restrict__ bs1, const float* __restrict__ bs2,
               int* __restrict__ bar, float* __restrict__ out)
{
  __shared__ float lred[16384];    // 64KB: dumps (cell*2+mtb)*4096; gred 64x129 reuses [0,8256)
  const int tid  = threadIdx.x;
  const int wv   = tid >> 6, lane = tid & 63;
  const int quad = lane >> 4, lc = lane & 15;
  const int mtb  = wv >> 1;        // wave's m-tile pair: {mtb*2, mtb*2+1}
  const int kh   = wv & 1;         // wave's K half
  const int bid  = blockIdx.x;
  const int jg   = bid >> 3;
  const int ht   = (bid & 7)*2 + (jg >> 4);   // XCD swizzle
  const int bt   = jg & 15;

  _Float16* const AOv[2] = {AO0, AO1};
  _Float16* const AFv[2] = {AF0, AF1};

  // epilogue ownership: b_loc = tid>>2 (row in 64-tile), oct = tid&3 (8-wide jj octet)
  const int b_loc = tid >> 2, oct = tid & 3;
  const int m = b_loc & 15, mtile_e = bt*4 + (b_loc >> 4);

  float c1s[8], c2s[8];
  #pragma unroll
  for (int i = 0; i < 8; i++) { c1s[i] = 0.f; c2s[i] = 0.f; }

  for (int r = 0; r < 162; r++) {
    const bool p1 = r < 129;
    const int  f  = r - 129;
    const int  wp = p1 ? (r & 1) : (f & 1);   // write parity
    const int  rp = wp ^ 1;                   // read parity
    const _Float16* A1 = p1 ? AOv[rp] : AFv[rp];  // cell1-part A
    const _Float16* A2 = AOv[rp];                  // cell2-part A
    const _Float16* B1 = p1 ? W1 : W2;
    const int wk1 = p1 ? 16 : 32;
    const int c1half = p1 ? 8 : 16;

    v4f acc1[2][8], acc2[2][8];
    #pragma unroll
    for (int i2 = 0; i2 < 2; i2++)
      #pragma unroll
      for (int tt = 0; tt < 8; tt++) { acc1[i2][tt] = (v4f){0,0,0,0}; acc2[i2][tt] = (v4f){0,0,0,0}; }

    const size_t mt0 = (size_t)(bt*4 + mtb*2) * 32;   // global mtile base (chunks)
    int ntg_[8];
    #pragma unroll
    for (int tt = 0; tt < 8; tt++) ntg_[tt] = (tt>>1)*32 + ht*2 + (tt&1);

    // ---- cell1-part GEMM (half-K) ----
    {
      const int c0 = kh * c1half;
      #pragma unroll 4
      for (int cc = 0; cc < c1half; cc++) {
        const int ch = c0 + cc;
        v8h av[2];
        #pragma unroll
        for (int i2 = 0; i2 < 2; i2++)
          av[i2] = ld_frag_dev(A1 + ((mt0 + i2*32 + ch) << 9) + lane*8);
        #pragma unroll
        for (int tt = 0; tt < 8; tt++) {
          v8h bv = *(const v8h*)(B1 + ((size_t)(ntg_[tt]*wk1 + ch) << 9) + lane*8);
          #pragma unroll
          for (int i2 = 0; i2 < 2; i2++)
            acc1[i2][tt] = __builtin_amdgcn_mfma_f32_16x16x32_f16(av[i2], bv, acc1[i2][tt], 0, 0, 0);
        }
      }
    }
    // ---- cell2-part GEMM (half of 32 chunks) ----
    {
      const int c0 = kh * 16;
      #pragma unroll 4
      for (int cc = 0; cc < 16; cc++) {
        const int ch = c0 + cc;
        v8h av[2];
        #pragma unroll
        for (int i2 = 0; i2 < 2; i2++)
          av[i2] = ld_frag_dev(A2 + ((mt0 + i2*32 + ch) << 9) + lane*8);
        #pragma unroll
        for (int tt = 0; tt < 8; tt++) {
          v8h bv = *(const v8h*)(W2 + ((size_t)(ntg_[tt]*32 + ch) << 9) + lane*8);
          #pragma unroll
          for (int i2 = 0; i2 < 2; i2++)
            acc2[i2][tt] = __builtin_amdgcn_mfma_f32_16x16x32_f16(av[i2], bv, acc2[i2][tt], 0, 0, 0);
        }
      }
    }

    // ---- K-reduce stage A: waves kh==1 dump BOTH cells (b128 stores) ----
    if (kh) {
      #pragma unroll
      for (int i2 = 0; i2 < 2; i2++)
        #pragma unroll
        for (int tt = 0; tt < 8; tt++) {
          const int sl = ((i2*8 + tt)*64 + lane)*4;
          *(v4f*)&lred[mtb*4096 + sl]        = acc1[i2][tt];
          *(v4f*)&lred[8192 + mtb*4096 + sl] = acc2[i2][tt];
        }
    }
    __syncthreads();
    // ---- stage B: waves kh==0 combine both cells into registers ----
    if (!kh) {
      #pragma unroll
      for (int i2 = 0; i2 < 2; i2++)
        #pragma unroll
        for (int tt = 0; tt < 8; tt++) {
          const int sl = ((i2*8 + tt)*64 + lane)*4;
          acc1[i2][tt] += *(const v4f*)&lred[mtb*4096 + sl];
          acc2[i2][tt] += *(const v4f*)&lred[8192 + mtb*4096 + sl];
        }
    }
    __syncthreads();

    // ---- per-cell: scatter -> sync -> epilogue -> sync ----
    #pragma unroll 1
    for (int cell = 0; cell < 2; cell++) {
      if (!kh) {                       // scatter combined acc into gred (pad-129 rows)
        v4f (*acc)[8] = cell ? acc2 : acc1;
        #pragma unroll
        for (int i2 = 0; i2 < 2; i2++)
          #pragma unroll
          for (int tt = 0; tt < 8; tt++) {
            int row = (mtb*2 + i2)*16 + quad*4;
            int col = tt*16 + lc;
            #pragma unroll
            for (int rr = 0; rr < 4; rr++) lred[(row + rr)*129 + col] = acc[i2][tt][rr];
          }
      }
      __syncthreads();

      // ---- epilogue: thread owns (b_loc, jj = oct*8..+7) ----
      const float* bsx = cell ? bs2 : (p1 ? bs1 : bs2);
      float g[4][8];
      #pragma unroll
      for (int g4 = 0; g4 < 4; g4++)
        #pragma unroll
        for (int j = 0; j < 8; j++)
          g[g4][j] = lred[b_loc*129 + g4*32 + oct*8 + j]
                   + bsx[g4*512 + ht*32 + oct*8 + j];

      const bool skipU = cell ? (r == 0 || r == 129) : (r == 128 || r == 161);
      if (cell == 0 && p1 && r < 128) {       // + x @ Wih1^T (K=4, exact fp32)
        const int b = bt*64 + b_loc;
        const v4f xv = *(const v4f*)(x + ((size_t)r*1024 + b)*4);
        #pragma unroll
        for (int g4 = 0; g4 < 4; g4++)
          #pragma unroll
          for (int j = 0; j < 8; j++) {
            int hh = ht*32 + oct*8 + j;
            const v4f w = *(const v4f*)(Wih1 + (size_t)(g4*512 + hh)*4);
            g[g4][j] += xv[0]*w[0] + xv[1]*w[1] + xv[2]*w[2] + xv[3]*w[3];
          }
      }

      if (!skipU) {
        float hfv[8];
        union { _Float16 h8[8]; unsigned long long u[2]; } hu;
        #pragma unroll
        for (int j = 0; j < 8; j++) {
          float ig = sigmoidf_(g[0][j]), fg = sigmoidf_(g[1][j]);
          float gg = tanhf_(g[2][j]),    og = sigmoidf_(g[3][j]);
          float c = cell ? c2s[j] : c1s[j];
          c = fg*c + ig*gg;
          if (cell) c2s[j] = c; else c1s[j] = c;
          hfv[j] = og * tanhf_(c);
          hu.h8[j] = (_Float16)hfv[j];
        }
        auto st16 = [&](_Float16* bp, int chunk) {
          unsigned long long* p = (unsigned long long*)
            (bp + (((size_t)(mtile_e*32 + chunk)) << 9) + (oct*16 + m)*8);
          __hip_atomic_store(p,     hu.u[0], __ATOMIC_RELAXED, __HIP_MEMORY_SCOPE_AGENT);
          __hip_atomic_store(p + 1, hu.u[1], __ATOMIC_RELAXED, __HIP_MEMORY_SCOPE_AGENT);
        };
        if (cell == 0) {               // h1(t) / h1f(s)
          if (p1) {
            st16(AOv[wp], ht);
            if (r == 127) st16(AFv[1], 16 + ht);   // h1(127) for f=0's h1f-GEMM
          } else {
            st16(AFv[wp], 16 + ht);
            st16(AOv[wp], ht);
          }
        } else {                       // h2(t-1) / h2f(s-1)
          st16(AOv[wp], 16 + ht);
          if (r == 128) { st16(AFv[0], ht); st16(AFv[1], ht); }  // tmp = h2(127)
        }

        if (cell == 1 && !p1) {        // out(s) = h2f(s) @ Wl^T + bl,  s = r-130
          const int s = r - 130;
          __syncthreads();             // all gate-reads of lred done
          #pragma unroll
          for (int j = 0; j < 8; j++) lred[b_loc*33 + oct*8 + j] = hfv[j];
          __syncthreads();
          int bb = tid >> 2, o = tid & 3;
          float sa = (ht == 0) ? blv[o] : 0.f;
          const float* wl = Wl + (size_t)o*512 + ht*32;
          #pragma unroll
          for (int jj = 0; jj < 32; jj++) sa += lred[bb*33 + jj] * wl[jj];
          atomicAdd(&out[(((size_t)s*1024) + bt*64 + bb)*4 + o], sa);
        }
      }
      __syncthreads();                 // gred free for next cell / next round
    }

    // ---- per-bt-group barrier: agent-relaxed add + relaxed poll ----
    if (tid == 0) {
      int* ctr = bar + bt*32;          // 128B-spaced counters
      __hip_atomic_fetch_add(ctr, 1, __ATOMIC_RELAXED, __HIP_MEMORY_SCOPE_AGENT);
      const int target = 16*(r+1);
      while (__hip_atomic_load(ctr, __ATOMIC_RELAXED, __HIP_MEMORY_SCOPE_AGENT) < target)
        __builtin_amdgcn_s_sleep(1);
    }
    __syncthreads();
  }
}

extern "C" void kernel_launch(void* const* d_in, const int* in_sizes, int n_in,
                              void* d_out, int out_size, void* d_ws, size_t ws_size,
                              hipStream_t stream) {
  const float* x    = (const float*)d_in[0];
  const float* Wih1 = (const float*)d_in[1];
  const float* Whh1 = (const float*)d_in[2];
  const float* bih1 = (const float*)d_in[3];
  const float* bhh1 = (const float*)d_in[4];
  const float* Wih2 = (const float*)d_in[5];
  const float* Whh2 = (const float*)d_in[6];
  const float* bih2 = (const float*)d_in[7];
  const float* bhh2 = (const float*)d_in[8];
  const float* Wl   = (const float*)d_in[9];
  const float* bl   = (const float*)d_in[10];

  char* ws = (char*)d_ws;
  int*      bar = (int*)(ws + OFF_BAR);
  _Float16* AO0 = (_Float16*)(ws + OFF_AO0);
  _Float16* AO1 = (_Float16*)(ws + OFF_AO1);
  _Float16* AF0 = (_Float16*)(ws + OFF_AF0);
  _Float16* AF1 = (_Float16*)(ws + OFF_AF1);
  _Float16* W1p = (_Float16*)(ws + OFF_W1);
  _Float16* W2p = (_Float16*)(ws + OFF_W2);
  float*    bs1 = (float*)(ws + OFF_B1);
  float*    bs2 = (float*)(ws + OFF_B2);

  // zero barrier + state buffers (h,c start at 0); zero out (atomic accumulation)
  hipMemsetAsync(ws, 0, (size_t)OFF_W1, stream);
  hipMemsetAsync(d_out, 0, (size_t)out_size * sizeof(float), stream);

  lstm_prep<<<2048, 256, 0, stream>>>(Whh1, Wih2, Whh2, bih1, bhh1, bih2, bhh2,
                                      W1p, W2p, bs1, bs2);
  lstm_main<<<256, 256, 0, stream>>>(x, Wih1, Wl, bl, AO0, AO1, AF0, AF1,
                                     W1p, W2p, bs1, bs2, bar, (float*)d_out);
}

// Round 6
// 3121.085 us; speedup vs baseline: 1.5976x; 1.5976x over previous
//
#include <hip/hip_runtime.h>

typedef _Float16 v8h __attribute__((ext_vector_type(8)));
typedef float v4f __attribute__((ext_vector_type(4)));
typedef unsigned int uint;

// ---- workspace layout (bytes) ----
#define OFF_BAR   0
#define OFF_AO0   4096
#define OFF_AO1   (OFF_AO0 + (1<<21))
#define OFF_AF0   (OFF_AO1 + (1<<21))
#define OFF_AF1   (OFF_AF0 + (1<<21))
#define OFF_W1    (OFF_AF1 + (1<<21))
#define OFF_W2    (OFF_W1 + (1<<21))
#define OFF_B1    (OFF_W2 + (1<<22))
#define OFF_B2    (OFF_B1 + 8192)

// Pack weights into MFMA B-fragment order:
// frag layout (16x16x32): n = nt*16 + (lane&15), k = k32*32 + (lane>>4)*8 + el
__global__ __launch_bounds__(256, 1)
void lstm_prep(const float* __restrict__ Whh1, const float* __restrict__ Wih2,
               const float* __restrict__ Whh2, const float* __restrict__ bih1,
               const float* __restrict__ bhh1, const float* __restrict__ bih2,
               const float* __restrict__ bhh2,
               _Float16* __restrict__ W1p, _Float16* __restrict__ W2p,
               float* __restrict__ bs1, float* __restrict__ bs2)
{
  const int total = 1048576 + 2097152 + 4096;
  for (int i = blockIdx.x*blockDim.x + threadIdx.x; i < total; i += gridDim.x*blockDim.x) {
    if (i < 1048576) {
      int nt = i >> 13, rem = i & 8191;
      int k32 = rem >> 9, c = rem & 511;
      int lane = c >> 3, el = c & 7;
      int n = nt*16 + (lane & 15);
      int k = k32*32 + (lane >> 4)*8 + el;
      W1p[i] = (_Float16)Whh1[n*512 + k];
    } else if (i < 3145728) {
      int j = i - 1048576;
      int nt = j >> 14, rem = j & 16383;
      int k32 = rem >> 9, c = rem & 511;
      int lane = c >> 3, el = c & 7;
      int n = nt*16 + (lane & 15);
      int k = k32*32 + (lane >> 4)*8 + el;
      float v = (k < 512) ? Wih2[n*512 + k] : Whh2[n*512 + (k - 512)];
      W2p[j] = (_Float16)v;
    } else {
      int n = i - 3145728;
      if (n < 2048) bs1[n] = bih1[n] + bhh1[n];
      else          bs2[n-2048] = bih2[n-2048] + bhh2[n-2048];
    }
  }
}

__device__ __forceinline__ float sigmoidf_(float z) { return 1.f / (1.f + __expf(-z)); }
__device__ __forceinline__ float tanhf_(float z)    { return 1.f - 2.f/(1.f + __expf(2.f*z)); }

// agent-scope relaxed 16B fragment load (2x8B): proven-correct exchange primitive
__device__ __forceinline__ v8h ld_frag_dev(const _Float16* base, uint off) {
  union { unsigned long long u[2]; v8h h; } cv;
  const unsigned long long* q = (const unsigned long long*)(base + off);
  cv.u[0] = __hip_atomic_load(q,     __ATOMIC_RELAXED, __HIP_MEMORY_SCOPE_AGENT);
  cv.u[1] = __hip_atomic_load(q + 1, __ATOMIC_RELAXED, __HIP_MEMORY_SCOPE_AGENT);
  return cv.h;
}

// 256 blocks x 512 threads (8 waves, 2/SIMD), persistent, fused pipeline (162 rounds).
// Wave split: cell(2) x mtile-pair(2) x K-half(2). Each SIMD co-schedules one
// cell1-wave (128 MFMA) + one cell2-wave (256 MFMA) -> 2x latency hiding vs R5.
// acc = 64 VGPR/wave -> compiler headroom for load pipelining.
// LDS (64KB): dump regions (cell*2+mtb)*4096 floats; gred 64x132 at [0,8448);
// stash 64x36 fp32 at [8448,10752) — lifetimes strictly sequenced by syncs.
__global__ __launch_bounds__(512, 2)
void lstm_main(const float* __restrict__ x, const float* __restrict__ Wih1,
               const float* __restrict__ Wl, const float* __restrict__ blv,
               _Float16* __restrict__ AO0, _Float16* __restrict__ AO1,
               _Float16* __restrict__ AF0, _Float16* __restrict__ AF1,
               const _Float16* __restrict__ W1, const _Float16* __restrict__ W2,
               const float* __restrict__ bs1, const float* __restrict__ bs2,
               int* __restrict__ bar, float* __restrict__ out)
{
  __shared__ float lred[16384];
  const int tid  = threadIdx.x;
  const int wv   = tid >> 6, lane = tid & 63;
  const int quad = lane >> 4, lc = lane & 15;
  const int cw   = wv & 1;          // which cell this wave's GEMM serves
  const int mtb  = (wv >> 1) & 1;   // m-tile pair {mtb*2, mtb*2+1}
  const int kh   = wv >> 2;         // K half
  const int bid  = blockIdx.x;
  const int jg   = bid >> 3;
  const int ht   = (bid & 7)*2 + (jg >> 4);   // XCD swizzle
  const int bt   = jg & 15;

  _Float16* const AOv[2] = {AO0, AO1};
  _Float16* const AFv[2] = {AF0, AF1};

  // epilogue-compute ownership (all 512): row erow, cols enib*4..+3
  const int erow = tid >> 3, enib = tid & 7;
  // store ownership (tid>=256): tid2 -> (b_loc, oct)
  const int tid2  = tid - 256;
  const int b_loc = (tid2 >= 0) ? (tid2 >> 2) : 0, oct = tid2 & 3;
  const int m     = b_loc & 15, mtile_e = bt*4 + (b_loc >> 4);
  const int STASH = 8448;

  int ntg_[8];
  #pragma unroll
  for (int tt = 0; tt < 8; tt++) ntg_[tt] = (tt>>1)*32 + ht*2 + (tt&1);

  float c1s[4], c2s[4];
  #pragma unroll
  for (int i = 0; i < 4; i++) { c1s[i] = 0.f; c2s[i] = 0.f; }

  for (int r = 0; r < 162; r++) {
    const bool p1 = r < 129;
    const int  f  = r - 129;
    const int  wp = p1 ? (r & 1) : (f & 1);   // write parity
    const int  rp = wp ^ 1;                   // read parity
    const _Float16* A1 = p1 ? AOv[rp] : AFv[rp];
    const _Float16* A2 = AOv[rp];
    const bool skip1 = (r == 128 || r == 161);
    const bool skip2 = (r == 0   || r == 129);

    // ---- this wave's GEMM ----
    const _Float16* Ac = cw ? A2 : A1;
    const _Float16* Bc = cw ? W2 : (p1 ? W1 : W2);
    const int wk   = cw ? 32 : (p1 ? 16 : 32);
    const int half = cw ? 16 : (p1 ? 8 : 16);
    const int ch0  = kh * half;

    v4f acc[2][8];
    #pragma unroll
    for (int i2 = 0; i2 < 2; i2++)
      #pragma unroll
      for (int tt = 0; tt < 8; tt++) acc[i2][tt] = (v4f){0,0,0,0};

    uint aoff[2];
    #pragma unroll
    for (int i2 = 0; i2 < 2; i2++)
      aoff[i2] = (uint)(((bt*4 + mtb*2 + i2)*32 + ch0)*512 + lane*8);
    uint boff[8];
    #pragma unroll
    for (int tt = 0; tt < 8; tt++)
      boff[tt] = (uint)((ntg_[tt]*wk + ch0)*512 + lane*8);

    #pragma unroll 4
    for (int cc = 0; cc < half; cc++) {
      v8h av[2];
      #pragma unroll
      for (int i2 = 0; i2 < 2; i2++)
        av[i2] = ld_frag_dev(Ac, aoff[i2] + cc*512);
      #pragma unroll
      for (int tt = 0; tt < 8; tt++) {
        v8h bv = *(const v8h*)(Bc + boff[tt] + cc*512);
        #pragma unroll
        for (int i2 = 0; i2 < 2; i2++)
          acc[i2][tt] = __builtin_amdgcn_mfma_f32_16x16x32_f16(av[i2], bv, acc[i2][tt], 0, 0, 0);
      }
    }

    // ---- K-reduce: kh=1 waves dump, kh=0 waves combine ----
    const int rbase = (cw*2 + mtb) * 4096;
    if (kh) {
      #pragma unroll
      for (int i2 = 0; i2 < 2; i2++)
        #pragma unroll
        for (int tt = 0; tt < 8; tt++)
          *(v4f*)&lred[rbase + ((i2*8 + tt)*64 + lane)*4] = acc[i2][tt];
    }
    __syncthreads();
    if (!kh) {
      #pragma unroll
      for (int i2 = 0; i2 < 2; i2++)
        #pragma unroll
        for (int tt = 0; tt < 8; tt++)
          acc[i2][tt] += *(const v4f*)&lred[rbase + ((i2*8 + tt)*64 + lane)*4];
    }
    __syncthreads();

    // ---- scatter cell1 into gred (stride 132) by waves wv0,wv2 ----
    if (!kh && cw == 0) {
      #pragma unroll
      for (int i2 = 0; i2 < 2; i2++)
        #pragma unroll
        for (int tt = 0; tt < 8; tt++) {
          int row = (mtb*2 + i2)*16 + quad*4;
          int col = tt*16 + lc;
          #pragma unroll
          for (int rr = 0; rr < 4; rr++) lred[(row + rr)*132 + col] = acc[i2][tt][rr];
        }
    }
    __syncthreads();

    // ================= epilogue cell1 (all 512 threads) =================
    {
      const float* bsx = p1 ? bs1 : bs2;
      float g[4][4];
      #pragma unroll
      for (int g4 = 0; g4 < 4; g4++) {
        v4f gv = *(const v4f*)&lred[erow*132 + g4*32 + enib*4];
        v4f bv = *(const v4f*)&bsx[g4*512 + ht*32 + enib*4];
        #pragma unroll
        for (int j = 0; j < 4; j++) g[g4][j] = gv[j] + bv[j];
      }
      if (p1 && r < 128) {             // + x @ Wih1^T (K=4, exact fp32)
        const v4f xv = *(const v4f*)(x + ((size_t)r*1024 + bt*64 + erow)*4);
        #pragma unroll
        for (int g4 = 0; g4 < 4; g4++)
          #pragma unroll
          for (int j = 0; j < 4; j++) {
            int hh = ht*32 + enib*4 + j;
            const v4f w = *(const v4f*)(Wih1 + (size_t)(g4*512 + hh)*4);
            g[g4][j] += xv[0]*w[0] + xv[1]*w[1] + xv[2]*w[2] + xv[3]*w[3];
          }
      }
      if (!skip1) {
        v4f hf;
        #pragma unroll
        for (int j = 0; j < 4; j++) {
          float ig = sigmoidf_(g[0][j]), fg = sigmoidf_(g[1][j]);
          float gg = tanhf_(g[2][j]),    og = sigmoidf_(g[3][j]);
          float c = fg*c1s[j] + ig*gg;
          c1s[j] = c;
          hf[j] = og * tanhf_(c);
        }
        *(v4f*)&lred[STASH + erow*36 + enib*4] = hf;
      }
    }
    __syncthreads();

    // ---- concurrent: store h1 (tid>=256, from stash) + scatter cell2 (wv1,wv3) ----
    if (tid >= 256 && !skip1) {
      v4f h0 = *(const v4f*)&lred[STASH + b_loc*36 + oct*8];
      v4f h1 = *(const v4f*)&lred[STASH + b_loc*36 + oct*8 + 4];
      union { _Float16 h8[8]; unsigned long long u[2]; } hu;
      #pragma unroll
      for (int j = 0; j < 4; j++) { hu.h8[j] = (_Float16)h0[j]; hu.h8[4+j] = (_Float16)h1[j]; }
      auto st16 = [&](_Float16* bp, int chunk) {
        unsigned long long* p = (unsigned long long*)
          (bp + (((size_t)(mtile_e*32 + chunk)) << 9) + (oct*16 + m)*8);
        __hip_atomic_store(p,     hu.u[0], __ATOMIC_RELAXED, __HIP_MEMORY_SCOPE_AGENT);
        __hip_atomic_store(p + 1, hu.u[1], __ATOMIC_RELAXED, __HIP_MEMORY_SCOPE_AGENT);
      };
      if (p1) {
        st16(AOv[wp], ht);
        if (r == 127) st16(AFv[1], 16 + ht);   // h1(127) for f=0's h1f-GEMM
      } else {
        st16(AFv[wp], 16 + ht);
        st16(AOv[wp], ht);
      }
    }
    if (!kh && cw == 1) {              // scatter cell2 into gred
      #pragma unroll
      for (int i2 = 0; i2 < 2; i2++)
        #pragma unroll
        for (int tt = 0; tt < 8; tt++) {
          int row = (mtb*2 + i2)*16 + quad*4;
          int col = tt*16 + lc;
          #pragma unroll
          for (int rr = 0; rr < 4; rr++) lred[(row + rr)*132 + col] = acc[i2][tt][rr];
        }
    }
    __syncthreads();

    // ================= epilogue cell2 (all 512 threads) =================
    {
      float g[4][4];
      #pragma unroll
      for (int g4 = 0; g4 < 4; g4++) {
        v4f gv = *(const v4f*)&lred[erow*132 + g4*32 + enib*4];
        v4f bv = *(const v4f*)&bs2[g4*512 + ht*32 + enib*4];
        #pragma unroll
        for (int j = 0; j < 4; j++) g[g4][j] = gv[j] + bv[j];
      }
      if (!skip2) {
        v4f hf;
        #pragma unroll
        for (int j = 0; j < 4; j++) {
          float ig = sigmoidf_(g[0][j]), fg = sigmoidf_(g[1][j]);
          float gg = tanhf_(g[2][j]),    og = sigmoidf_(g[3][j]);
          float c = fg*c2s[j] + ig*gg;
          c2s[j] = c;
          hf[j] = og * tanhf_(c);
        }
        *(v4f*)&lred[STASH + erow*36 + enib*4] = hf;
      }
    }
    __syncthreads();

    // ---- store h2 (tid>=256) + out-projection (tid<256, phase2) ----
    if (tid >= 256 && !skip2) {
      v4f h0 = *(const v4f*)&lred[STASH + b_loc*36 + oct*8];
      v4f h1 = *(const v4f*)&lred[STASH + b_loc*36 + oct*8 + 4];
      union { _Float16 h8[8]; unsigned long long u[2]; } hu;
      #pragma unroll
      for (int j = 0; j < 4; j++) { hu.h8[j] = (_Float16)h0[j]; hu.h8[4+j] = (_Float16)h1[j]; }
      auto st16 = [&](_Float16* bp, int chunk) {
        unsigned long long* p = (unsigned long long*)
          (bp + (((size_t)(mtile_e*32 + chunk)) << 9) + (oct*16 + m)*8);
        __hip_atomic_store(p,     hu.u[0], __ATOMIC_RELAXED, __HIP_MEMORY_SCOPE_AGENT);
        __hip_atomic_store(p + 1, hu.u[1], __ATOMIC_RELAXED, __HIP_MEMORY_SCOPE_AGENT);
      };
      st16(AOv[wp], 16 + ht);
      if (r == 128) { st16(AFv[0], ht); st16(AFv[1], ht); }   // tmp = h2(127)
    }
    if (tid < 256 && !p1 && r >= 130) {  // out(s) = h2f(s) @ Wl^T + bl, s = r-130
      const int s = r - 130;
      int bb = tid >> 2, o = tid & 3;
      float sa = (ht == 0) ? blv[o] : 0.f;
      const float* wl = Wl + (size_t)o*512 + ht*32;
      #pragma unroll
      for (int jj = 0; jj < 32; jj++) sa += lred[STASH + bb*36 + jj] * wl[jj];
      atomicAdd(&out[(((size_t)s*1024) + bt*64 + bb)*4 + o], sa);
    }
    __syncthreads();

    // ---- per-bt-group barrier: agent-relaxed add + relaxed poll ----
    if (tid == 0) {
      int* ctr = bar + bt*32;          // 128B-spaced counters
      __hip_atomic_fetch_add(ctr, 1, __ATOMIC_RELAXED, __HIP_MEMORY_SCOPE_AGENT);
      const int target = 16*(r+1);
      while (__hip_atomic_load(ctr, __ATOMIC_RELAXED, __HIP_MEMORY_SCOPE_AGENT) < target)
        __builtin_amdgcn_s_sleep(1);
    }
    __syncthreads();
  }
}

extern "C" void kernel_launch(void* const* d_in, const int* in_sizes, int n_in,
                              void* d_out, int out_size, void* d_ws, size_t ws_size,
                              hipStream_t stream) {
  const float* x    = (const float*)d_in[0];
  const float* Wih1 = (const float*)d_in[1];
  const float* Whh1 = (const float*)d_in[2];
  const float* bih1 = (const float*)d_in[3];
  const float* bhh1 = (const float*)d_in[4];
  const float* Wih2 = (const float*)d_in[5];
  const float* Whh2 = (const float*)d_in[6];
  const float* bih2 = (const float*)d_in[7];
  const float* bhh2 = (const float*)d_in[8];
  const float* Wl   = (const float*)d_in[9];
  const float* bl   = (const float*)d_in[10];

  char* ws = (char*)d_ws;
  int*      bar = (int*)(ws + OFF_BAR);
  _Float16* AO0 = (_Float16*)(ws + OFF_AO0);
  _Float16* AO1 = (_Float16*)(ws + OFF_AO1);
  _Float16* AF0 = (_Float16*)(ws + OFF_AF0);
  _Float16* AF1 = (_Float16*)(ws + OFF_AF1);
  _Float16* W1p = (_Float16*)(ws + OFF_W1);
  _Float16* W2p = (_Float16*)(ws + OFF_W2);
  float*    bs1 = (float*)(ws + OFF_B1);
  float*    bs2 = (float*)(ws + OFF_B2);

  // zero barrier + state buffers (h,c start at 0); zero out (atomic accumulation)
  hipMemsetAsync(ws, 0, (size_t)OFF_W1, stream);
  hipMemsetAsync(d_out, 0, (size_t)out_size * sizeof(float), stream);

  lstm_prep<<<2048, 256, 0, stream>>>(Whh1, Wih2, Whh2, bih1, bhh1, bih2, bhh2,
                                      W1p, W2p, bs1, bs2);
  lstm_main<<<256, 512, 0, stream>>>(x, Wih1, Wl, bl, AO0, AO1, AF0, AF1,
                                     W1p, W2p, bs1, bs2, bar, (float*)d_out);
}